// Round 13
// baseline (36.142 us; speedup 1.0000x reference)
//
#include <hip/hip_runtime.h>

#define N 512
#define U_CNT 128
#define F_STRIDE 80
#define TOPK 10
#define W 32                  // half band width (sorted space)
#define PAD 64
#define BSZ (PAD + N + PAD)   // 640
#define NCH ((2 * W + 4) / 4) // 17 band float4 chunks
#define BAND (2 * W + 4)      // 68
// log2(e)/tau with tau = 0.1
#define L2T 14.426950408889634f
#define LOG2E 1.4426950408889634f
#define NEGBIG -1.0e30f

#if defined(__has_builtin)
#if __has_builtin(__builtin_amdgcn_exp2f)
#define EXP2F(x) __builtin_amdgcn_exp2f(x)
#endif
#if __has_builtin(__builtin_amdgcn_logf)
#define LOG2F(x) __builtin_amdgcn_logf(x)
#endif
#endif
#ifndef EXP2F
#define EXP2F(x) exp2f(x)
#endif
#ifndef LOG2F
#define LOG2F(x) log2f(x)
#endif

// monotone u32 key: ascending key == ascending float (no NaN/-0 in inputs)
__device__ __forceinline__ unsigned key32(float x) {
  unsigned bb = __float_as_uint(x);
  return bb ^ ((unsigned)((int)bb >> 31) | 0x80000000u);
}

// One block per (user, which), 512 threads. Thread t owns sorted row/col t.
// LINEAR-domain banded Sinkhorn: P = diag(r) * P0 * diag(c), with thread t's
// kernel bands Krow[j]=P0[t][j], Kcol[i]=P0[i][t] cached in VGPRs (constant
// across all passes). Each pass after col-1: 17 ds_read_b128 + 68 fma.
// Rank pass: u32 keys, 4/b128 read; descending rank = #{>} with exact
// rare slow path for true ties (eqc>1). Band truncation W=32 validated
// r10-r12 (absmax at/below quantization floor).
__global__ __launch_bounds__(512, 2) void loss_kernel(
    const float* __restrict__ batch, const float* __restrict__ sdiv,
    const float* __restrict__ sndcg, const float* __restrict__ rel,
    float* __restrict__ out) {
  __shared__ __align__(16) unsigned sh_k32[N];   // score keys
  __shared__ __align__(16) unsigned sh_k32b[N];  // rel keys (ndcg)
  __shared__ __align__(16) float sh_sv[N];    // sorted raw score
  __shared__ __align__(16) int sh_pos[N];     // rank -> orig index
  __shared__ __align__(16) float sh_Qs[BSZ];  // sorted qs (pad 0)
  __shared__ __align__(16) float sh_Uu[BSZ];  // u0 log col init (pad -1e30)
  __shared__ __align__(16) float sh_Rl[BSZ];  // rl0 log row init (pad -1e30)
  __shared__ __align__(16) float sh_r[BSZ];   // linear row scale (pad 0)
  __shared__ __align__(16) float sh_c[BSZ];   // linear col scale (pad 0)
  __shared__ __align__(16) float sh_lw[BSZ];  // fin=u0+log2(c) | wr=(N-i)*r
  __shared__ __align__(16) float sh_relS[N];  // rel sorted by score rank
  __shared__ __align__(16) float sh_aux[N];   // arj orig (div)
  __shared__ __align__(16) float sh_inv[N];
  __shared__ __align__(16) float sh_rr[N];
  __shared__ __align__(16) float sh_pA[N];
  __shared__ __align__(16) float sh_pB[N];
  __shared__ float sh_red[8];
  __shared__ float sh_w1[8], sh_w2[8], sh_w3[8], sh_w4[8], sh_w5[8];
  __shared__ float sh_row[TOPK];

  const int b = blockIdx.x;
  const int u = b >> 1;
  const int which = b & 1;
  const int t = threadIdx.x;
  const int wv = t >> 6;
  const int ln = t & 63;

  // pad init (log sentinels NEGBIG; linear sentinels 0)
  if (t < PAD) {
    sh_Qs[t] = 0.f; sh_Uu[t] = NEGBIG; sh_Rl[t] = NEGBIG;
    sh_r[t] = 0.f; sh_c[t] = 0.f;
    sh_lw[t] = which ? 0.f : NEGBIG;
  } else if (t < 2 * PAD) {
    int p = N + t;  // PAD + N + (t - PAD)
    sh_Qs[p] = 0.f; sh_Uu[p] = NEGBIG; sh_Rl[p] = NEGBIG;
    sh_r[p] = 0.f; sh_c[p] = 0.f;
    sh_lw[p] = which ? 0.f : NEGBIG;
  }

  const float sj = ((which ? sdiv : sndcg) + (size_t)u * N)[t];
  sh_k32[t] = key32(sj);
  float rv = 0.f;
  if (!which) {
    rv = rel[(size_t)u * N + t];
    sh_k32b[t] = key32(rv);
  }
  float ssq = 0.f;
  if (which) {  // early item-norm: global latency hides under rank pass
    const float4* it4 =
        (const float4*)(batch + (size_t)(u * N + t) * F_STRIDE);
#pragma unroll
    for (int f4 = 0; f4 < 16; f4++) {
      float4 p = it4[f4];
      ssq = fmaf(p.x, p.x, ssq); ssq = fmaf(p.y, p.y, ssq);
      ssq = fmaf(p.z, p.z, ssq); ssq = fmaf(p.w, p.w, ssq);
    }
  }
  __syncthreads();

  // ---- rank pass: u32 counting (4 keys / b128); ndcg fuses rel-rank ----
  int rnk2 = 0;
  {
    const unsigned myk = sh_k32[t];
    const uint4* k4p = (const uint4*)sh_k32;
    int gtc = 0, eqc = 0;
    if (!which) {
      const unsigned myk2 = sh_k32b[t];
      const uint4* k4b = (const uint4*)sh_k32b;
      int gt2 = 0, eq2 = 0;
#pragma unroll 8
      for (int i = 0; i < N / 4; i++) {
        uint4 kk = k4p[i], kb = k4b[i];
        gtc += (kk.x > myk) + (kk.y > myk) + (kk.z > myk) + (kk.w > myk);
        eqc += (kk.x == myk) + (kk.y == myk) + (kk.z == myk) + (kk.w == myk);
        gt2 += (kb.x > myk2) + (kb.y > myk2) + (kb.z > myk2) + (kb.w > myk2);
        eq2 += (kb.x == myk2) + (kb.y == myk2) + (kb.z == myk2) + (kb.w == myk2);
      }
      rnk2 = gt2;
      if (eq2 > 1) {  // rare true tie in rel: exact stable fix-up
        for (int k = 0; k < t; k++) rnk2 += (sh_k32b[k] == myk2);
      }
    } else {
#pragma unroll 8
      for (int i = 0; i < N / 4; i++) {
        uint4 kk = k4p[i];
        gtc += (kk.x > myk) + (kk.y > myk) + (kk.z > myk) + (kk.w > myk);
        eqc += (kk.x == myk) + (kk.y == myk) + (kk.z == myk) + (kk.w == myk);
      }
    }
    int rnk = gtc;
    if (eqc > 1) {  // rare true tie in score: exact stable fix-up
      for (int k = 0; k < t; k++) rnk += (sh_k32[k] == myk);
    }
    sh_sv[rnk] = sj;
    sh_pos[rnk] = t;
    if (!which) sh_relS[rnk] = rv;  // direct scatter, no gather later
  }
  __syncthreads();

  // ---- sorted-space setup: Qs, asum via prefix scan -> u0 ----
  const float sv = sh_sv[t];
  sh_Qs[PAD + t] = sv * L2T;
  {
    float ps = sv;  // inclusive wave scan
#pragma unroll
    for (int m = 1; m <= 32; m <<= 1) {
      float o = __shfl_up(ps, m, 64);
      if (ln >= m) ps += o;
    }
    if (ln == 63) sh_red[wv] = ps;
    __syncthreads();
    float off = 0.f, Tt = 0.f;
#pragma unroll
    for (int w2 = 0; w2 < 8; w2++) {
      float rw = sh_red[w2];
      if (w2 < wv) off += rw;
      Tt += rw;
    }
    float S = ps + off;  // inclusive prefix over block (desc sorted)
    float asum = 2.f * S - Tt + (float)(N - 2 - 2 * t) * sv;
    sh_Uu[PAD + t] = -asum * L2T;
  }
  __syncthreads();

  // band geometry (float4-aligned, covers [t-W, t+W])
  const int base = (t & ~3) - W;  // PAD+base >= 32, multiple of 4
  const float vi = 511.f - 2.f * (float)t;

  float4 Krow[NCH], Kcol[NCH];
  float rt = 1.f, ct;

  // ---- init row softmax: build Krow (linear, row-stochastic) + rl0 ----
  {
    float e0 = fmaf(vi, sh_Qs[PAD + t - 1], sh_Uu[PAD + t - 1]);
    float e1 = fmaf(vi, sh_Qs[PAD + t], sh_Uu[PAD + t]);
    float e2 = fmaf(vi, sh_Qs[PAD + t + 1], sh_Uu[PAD + t + 1]);
    float em = -fmaxf(e1, fmaxf(e0, e2));
    const float4* q4 = (const float4*)(sh_Qs + PAD + base);
    const float4* u4 = (const float4*)(sh_Uu + PAD + base);
    float z0 = 0.f, z1 = 0.f, z2 = 0.f, z3 = 0.f;
#pragma unroll
    for (int c = 0; c < NCH; c++) {
      float4 a = q4[c], cc = u4[c];
      float t0 = EXP2F(fmaf(vi, a.x, cc.x) + em);
      float t1 = EXP2F(fmaf(vi, a.y, cc.y) + em);
      float t2 = EXP2F(fmaf(vi, a.z, cc.z) + em);
      float t3 = EXP2F(fmaf(vi, a.w, cc.w) + em);
      Krow[c].x = t0; Krow[c].y = t1; Krow[c].z = t2; Krow[c].w = t3;
      z0 += t0; z1 += t1; z2 += t2; z3 += t3;
    }
    float Z = (z0 + z2) + (z1 + z3);
    float invZ = 1.f / Z;
    sh_Rl[PAD + t] = em - LOG2F(Z);
#pragma unroll
    for (int c = 0; c < NCH; c++) {
      Krow[c].x *= invZ; Krow[c].y *= invZ;
      Krow[c].z *= invZ; Krow[c].w *= invZ;
    }
  }
  __syncthreads();

  // ---- col pass 1 (log-domain, builds Kcol) -> linear c ----
  {
    const float qsr = sh_Qs[PAD + t];
    const float c0 = sh_Uu[PAD + t];
    const float4* r4 = (const float4*)(sh_Rl + PAD + base);
    float a0 = 0.f, a1 = 0.f, a2 = 0.f, a3 = 0.f;
    float v = 511.f - 2.f * (float)base;
#pragma unroll
    for (int c = 0; c < NCH; c++) {
      float4 r = r4[c];
      float t0 = EXP2F(fmaf(v, qsr, c0) + r.x); v -= 2.f;
      float t1 = EXP2F(fmaf(v, qsr, c0) + r.y); v -= 2.f;
      float t2 = EXP2F(fmaf(v, qsr, c0) + r.z); v -= 2.f;
      float t3 = EXP2F(fmaf(v, qsr, c0) + r.w); v -= 2.f;
      Kcol[c].x = t0; Kcol[c].y = t1; Kcol[c].z = t2; Kcol[c].w = t3;
      a0 += t0; a1 += t1; a2 += t2; a3 += t3;
    }
    float A = (a0 + a2) + (a1 + a3);  // true col sum (r=1, c=1)
    ct = 1.f / fmaxf(A, 1e-10f);
    sh_c[PAD + t] = ct;
  }
  __syncthreads();

  // ---- linear Sinkhorn: row1..row5, col2..col5 (fma-only passes) ----
#pragma unroll 1
  for (int it = 0; it < 5; it++) {
    {  // row pass: A = sum Krow * c-band
      const float4* c4 = (const float4*)(sh_c + PAD + base);
      float a0 = 0.f, a1 = 0.f, a2 = 0.f, a3 = 0.f;
#pragma unroll
      for (int c = 0; c < NCH; c++) {
        float4 cc = c4[c];
        a0 = fmaf(Krow[c].x, cc.x, a0);
        a1 = fmaf(Krow[c].y, cc.y, a1);
        a2 = fmaf(Krow[c].z, cc.z, a2);
        a3 = fmaf(Krow[c].w, cc.w, a3);
      }
      float A = (a0 + a2) + (a1 + a3);
      float trues = rt * A;  // true row sum of current matrix
      rt = rt / fmaxf(trues, 1e-10f);
      sh_r[PAD + t] = rt;
      if (it == 4) {  // final state: prep tail arrays
        if (which)
          sh_lw[PAD + t] = (float)(N - t) * rt;          // wr for approx_rank
        else
          sh_lw[PAD + t] = sh_Uu[PAD + t] + LOG2F(ct);   // fin = u0 + log2(c)
      }
    }
    __syncthreads();
    if (it < 4) {
      {  // col pass: A = sum Kcol * r-band
        const float4* r4 = (const float4*)(sh_r + PAD + base);
        float a0 = 0.f, a1 = 0.f, a2 = 0.f, a3 = 0.f;
#pragma unroll
        for (int c = 0; c < NCH; c++) {
          float4 rr = r4[c];
          a0 = fmaf(Kcol[c].x, rr.x, a0);
          a1 = fmaf(Kcol[c].y, rr.y, a1);
          a2 = fmaf(Kcol[c].z, rr.z, a2);
          a3 = fmaf(Kcol[c].w, rr.w, a3);
        }
        float A = (a0 + a2) + (a1 + a3);
        float trues = ct * A;  // true col sum of current matrix
        ct = ct / fmaxf(trues, 1e-10f);
        sh_c[PAD + t] = ct;
      }
      __syncthreads();
    }
  }

  if (which == 0) {
    // ===================== NDCG path =====================
    // wave-per-row approx_rel: P[r][j] = exp2(cv*qs_j + fin_j + rl0_r) * r_r
#pragma unroll
    for (int r = wv; r < TOPK; r += 8) {
      const float cv = 511.f - 2.f * (float)r;
      const float rl = sh_Rl[PAD + r];
      const float rr = sh_r[PAD + r];
      const int rbase = (r & ~3) - W;
      float srel = 0.f;
#pragma unroll
      for (int k = 0; k < 2; k++) {
        int e = ln + 64 * k;
        if (e < BAND) {
          int j = rbase + e;
          float ex = fmaf(cv, sh_Qs[PAD + j], sh_lw[PAD + j]) + rl;
          float rv2 = ((unsigned)j < N) ? sh_relS[j] : 0.f;
          srel = fmaf(EXP2F(ex), rv2, srel);
        }
      }
#pragma unroll
      for (int mm = 32; mm >= 1; mm >>= 1) srel += __shfl_xor(srel, mm, 64);
      if (ln == 0) sh_row[r] = srel * rr;
    }
    // dcg contrib: sorted position t holds the item at descending rank t
    float cd = (t < TOPK)
        ? (EXP2F(sh_relS[t]) - 1.f) / LOG2F((float)(t + 2)) : 0.f;
    // bdcg: rank from fused loop (rnk2), rel value still in register
    float cb = 0.f;
    if (rnk2 < TOPK) cb = (EXP2F(rv) - 1.f) / LOG2F((float)(rnk2 + 2));
    // dual interleaved wave reduce (dcg, bdcg)
#pragma unroll
    for (int mm = 32; mm >= 1; mm >>= 1) {
      cd += __shfl_xor(cd, mm, 64);
      cb += __shfl_xor(cb, mm, 64);
    }
    if (ln == 0) { sh_w1[wv] = cd; sh_w2[wv] = cb; }
    __syncthreads();
    if (t == 0) {
      float adcg = 0.f;
#pragma unroll
      for (int r = 0; r < TOPK; r++)
        adcg += (EXP2F(sh_row[r]) - 1.f) / LOG2F((float)(r + 2));
      float dcg = 0.f, bdcg = 0.f;
#pragma unroll
      for (int w2 = 0; w2 < 8; w2++) { dcg += sh_w1[w2]; bdcg += sh_w2[w2]; }
      out[u] = adcg / bdcg;
      out[U_CNT + u] = dcg / bdcg;
    }
  } else {
    // ===================== Diversity path =====================
    {  // approx_rank: ar_t = ct * sum_i Kcol[i] * wr[i]  (fma-only)
      const float4* l4 = (const float4*)(sh_lw + PAD + base);
      float a0 = 0.f, a1 = 0.f, a2 = 0.f, a3 = 0.f;
#pragma unroll
      for (int c = 0; c < NCH; c++) {
        float4 r = l4[c];
        a0 = fmaf(Kcol[c].x, r.x, a0);
        a1 = fmaf(Kcol[c].y, r.y, a1);
        a2 = fmaf(Kcol[c].z, r.z, a2);
        a3 = fmaf(Kcol[c].w, r.w, a3);
      }
      float ar = ct * ((a0 + a2) + (a1 + a3));
      float arj_s = 1.f / (1.f + EXP2F((502.f - ar) * LOG2E));  // sigmoid
      int o = sh_pos[t];
      sh_aux[o] = arj_s;                  // scatter to orig item index
      sh_rr[o] = (t < TOPK) ? 1.f : 0.f;  // desc rank < 10 -> top-10
    }
    float inv = 1.f / fmaxf(sqrtf(ssq), 1e-8f);  // orig item t (early ssq)
    sh_inv[t] = inv;
    float om = 1.f - ssq * inv * inv;  // 1 - ||n||^2 for ORIG item t
    __syncthreads();
    float arj = sh_aux[t], rrj = sh_rr[t];
    float r1 = arj, r2 = arj * arj, r3 = arj * arj * om, r4v = rrj,
          r5v = rrj * om;
#pragma unroll
    for (int mm = 32; mm >= 1; mm >>= 1) {
      r1 += __shfl_xor(r1, mm, 64);
      r2 += __shfl_xor(r2, mm, 64);
      r3 += __shfl_xor(r3, mm, 64);
      r4v += __shfl_xor(r4v, mm, 64);
      r5v += __shfl_xor(r5v, mm, 64);
    }
    if (ln == 0) {
      sh_w1[wv] = r1; sh_w2[wv] = r2; sh_w3[wv] = r3;
      sh_w4[wv] = r4v; sh_w5[wv] = r5v;
    }
    // V = sum_j a_j * n_j (64-dim): wave wv handles 64 j's, lane = feature
    const float* bu = batch + (size_t)u * N * F_STRIDE;
    float va = 0.f, vr = 0.f;
#pragma unroll 8
    for (int jj = 0; jj < 64; jj++) {
      int j2 = (wv << 6) + jj;
      float x = bu[(size_t)j2 * F_STRIDE + ln] * sh_inv[j2];
      va = fmaf(sh_aux[j2], x, va);
      vr = fmaf(sh_rr[j2], x, vr);
    }
    sh_pA[t] = va;
    sh_pB[t] = vr;
    __syncthreads();
    float qa = 0.f, qr = 0.f;
    if (t < 64) {
      float VA = 0.f, VR = 0.f;
#pragma unroll
      for (int c2 = 0; c2 < 8; c2++) {
        VA += sh_pA[c2 * 64 + t];
        VR += sh_pB[c2 * 64 + t];
      }
      qa = VA * VA;
      qr = VR * VR;
    }
#pragma unroll
    for (int mm = 32; mm >= 1; mm >>= 1) {
      qa += __shfl_xor(qa, mm, 64);
      qr += __shfl_xor(qr, mm, 64);
    }
    if (t == 0) {  // qa/qr complete in wave 0; sh_w* visible since last bar
      float S1a = 0.f, S2a = 0.f, DA = 0.f, S1r = 0.f, DR = 0.f;
#pragma unroll
      for (int w2 = 0; w2 < 8; w2++) {
        S1a += sh_w1[w2]; S2a += sh_w2[w2]; DA += sh_w3[w2];
        S1r += sh_w4[w2]; DR += sh_w5[w2];
      }
      // sum_{i<j} a_i a_j (1 - n_i.n_j) = 0.5*(S1^2 - ||V||^2 - diag)
      float numA = 0.5f * (S1a * S1a - qa - DA);
      float denA = 0.5f * (S1a * S1a - S2a);
      out[2 * U_CNT + u] = numA / denA;
      float numR = 0.5f * (S1r * S1r - qr - DR);
      float denR = 0.5f * (S1r * S1r - S1r);
      out[3 * U_CNT + u] = numR / denR;
    }
  }
}

extern "C" void kernel_launch(void* const* d_in, const int* in_sizes, int n_in,
                              void* d_out, int out_size, void* d_ws,
                              size_t ws_size, hipStream_t stream) {
  (void)in_sizes; (void)n_in; (void)d_ws; (void)ws_size; (void)out_size;
  const float* batch = (const float*)d_in[0];
  const float* sdiv = (const float*)d_in[1];
  const float* sndcg = (const float*)d_in[2];
  const float* rel = (const float*)d_in[3];
  float* out = (float*)d_out;
  loss_kernel<<<dim3(U_CNT * 2), dim3(N), 0, stream>>>(batch, sdiv, sndcg, rel,
                                                       out);
}

// Round 14
// 28.067 us; speedup vs baseline: 1.2877x; 1.2877x over previous
//
#include <hip/hip_runtime.h>

#define N 512
#define U_CNT 128
#define F_STRIDE 80
#define TOPK 10
#define W 32                  // half band width (sorted space)
#define PAD 64
#define BSZ (PAD + N + PAD)   // 640
#define NCH ((2 * W + 4) / 4) // 17 band float4 chunks
#define BAND (2 * W + 4)      // 68
// log2(e)/tau with tau = 0.1
#define L2T 14.426950408889634f
#define LOG2E 1.4426950408889634f
#define NEGBIG -1.0e30f

#if defined(__has_builtin)
#if __has_builtin(__builtin_amdgcn_exp2f)
#define EXP2F(x) __builtin_amdgcn_exp2f(x)
#endif
#if __has_builtin(__builtin_amdgcn_logf)
#define LOG2F(x) __builtin_amdgcn_logf(x)
#endif
#endif
#ifndef EXP2F
#define EXP2F(x) exp2f(x)
#endif
#ifndef LOG2F
#define LOG2F(x) log2f(x)
#endif

// monotone sortable key: ascending key order == descending value order,
// ties broken by smaller idx first (stable, matches jnp.argsort on -score)
__device__ __forceinline__ unsigned long long sortkey(float x, int idx) {
  unsigned int bb = __float_as_uint(x);
  bb ^= (unsigned int)((int)bb >> 31) | 0x80000000u;
  return ((unsigned long long)(~bb) << 10) | (unsigned long long)idx;
}

// One block per (user, which), 512 threads. Thread t owns sorted row/col t.
// LINEAR-domain banded Sinkhorn: P = diag(r) * P0 * diag(c), with thread t's
// kernel bands Krow[j]=P0[t][j], Kcol[i]=P0[i][t] cached in VGPRs (constant
// across all passes). Each pass after col-1: 17 ds_read_b128 + 68 fma, no
// exp2/log2. Rank passes: u64 keys (1 cmp/elem — u32 variants lose on VALU,
// verified r10+r13). Band truncation W=32 validated r10-r12.
__global__ __launch_bounds__(512, 2) void loss_kernel(
    const float* __restrict__ batch, const float* __restrict__ sdiv,
    const float* __restrict__ sndcg, const float* __restrict__ rel,
    float* __restrict__ out) {
  __shared__ __align__(16) unsigned long long sh_key[N];   // score keys
  __shared__ __align__(16) unsigned long long sh_key2[N];  // rel keys (ndcg)
  __shared__ __align__(16) float sh_sv[N];    // sorted raw score
  __shared__ __align__(16) int sh_pos[N];     // rank -> orig index
  __shared__ __align__(16) float sh_Qs[BSZ];  // sorted qs (pad 0)
  __shared__ __align__(16) float sh_Uu[BSZ];  // u0 log col init (pad -1e30)
  __shared__ __align__(16) float sh_Rl[BSZ];  // rl0 log row init (pad -1e30)
  __shared__ __align__(16) float sh_r[BSZ];   // linear row scale (pad 0)
  __shared__ __align__(16) float sh_c[BSZ];   // linear col scale (pad 0)
  __shared__ __align__(16) float sh_lw[BSZ];  // fin=u0+log2(c) | wr=(N-i)*r
  __shared__ __align__(16) float sh_relS[N];  // rel sorted by score rank
  __shared__ __align__(16) float sh_aux[N];   // rel orig (ndcg) | arj (div)
  __shared__ __align__(16) float sh_inv[N];
  __shared__ __align__(16) float sh_rr[N];
  __shared__ __align__(16) float sh_pA[N];
  __shared__ __align__(16) float sh_pB[N];
  __shared__ float sh_red[8];
  __shared__ float sh_w1[8], sh_w2[8], sh_w3[8], sh_w4[8], sh_w5[8];
  __shared__ float sh_row[TOPK];
  __shared__ float sh_invd[16];  // 1/log2(r+2), r<16

  const int b = blockIdx.x;
  const int u = b >> 1;
  const int which = b & 1;
  const int t = threadIdx.x;
  const int wv = t >> 6;
  const int ln = t & 63;

  // pad init (log sentinels NEGBIG; linear sentinels 0) + discount table
  if (t < PAD) {
    sh_Qs[t] = 0.f; sh_Uu[t] = NEGBIG; sh_Rl[t] = NEGBIG;
    sh_r[t] = 0.f; sh_c[t] = 0.f;
    sh_lw[t] = which ? 0.f : NEGBIG;
    if (t < 16) sh_invd[t] = 1.f / LOG2F((float)(t + 2));
  } else if (t < 2 * PAD) {
    int p = N + t;  // PAD + N + (t - PAD)
    sh_Qs[p] = 0.f; sh_Uu[p] = NEGBIG; sh_Rl[p] = NEGBIG;
    sh_r[p] = 0.f; sh_c[p] = 0.f;
    sh_lw[p] = which ? 0.f : NEGBIG;
  }

  const float sj = ((which ? sdiv : sndcg) + (size_t)u * N)[t];
  sh_key[t] = sortkey(sj, t);
  float rv = 0.f;
  if (!which) {
    rv = rel[(size_t)u * N + t];
    sh_aux[t] = rv;
    sh_key2[t] = sortkey(rv, t);
  }
  float ssq = 0.f;
  if (which) {  // early item-norm: global latency hides under rank pass
    const float4* it4 =
        (const float4*)(batch + (size_t)(u * N + t) * F_STRIDE);
#pragma unroll
    for (int f4 = 0; f4 < 16; f4++) {
      float4 p = it4[f4];
      ssq = fmaf(p.x, p.x, ssq); ssq = fmaf(p.y, p.y, ssq);
      ssq = fmaf(p.z, p.z, ssq); ssq = fmaf(p.w, p.w, ssq);
    }
  }
  __syncthreads();

  // ---- rank pass: u64 key counting; ndcg fuses rel-rank in same loop ----
  int rnk2 = 0;
  {
    const unsigned long long myk = sh_key[t];
    const ulonglong2* k2 = (const ulonglong2*)sh_key;
    int rnk = 0;
    if (!which) {
      const unsigned long long myk2 = sh_key2[t];
      const ulonglong2* k2b = (const ulonglong2*)sh_key2;
#pragma unroll 8
      for (int i = 0; i < N / 2; i++) {
        ulonglong2 kk = k2[i], kb = k2b[i];
        rnk += (kk.x < myk) + (kk.y < myk);
        rnk2 += (kb.x < myk2) + (kb.y < myk2);
      }
    } else {
#pragma unroll 8
      for (int i = 0; i < N / 2; i++) {
        ulonglong2 kk = k2[i];
        rnk += (kk.x < myk) + (kk.y < myk);
      }
    }
    sh_sv[rnk] = sj;
    sh_pos[rnk] = t;
    if (!which) sh_relS[rnk] = rv;  // direct scatter
  }
  __syncthreads();

  // ---- sorted-space setup: Qs, asum via prefix scan -> u0 ----
  const float sv = sh_sv[t];
  sh_Qs[PAD + t] = sv * L2T;
  {
    float ps = sv;  // inclusive wave scan
#pragma unroll
    for (int m = 1; m <= 32; m <<= 1) {
      float o = __shfl_up(ps, m, 64);
      if (ln >= m) ps += o;
    }
    if (ln == 63) sh_red[wv] = ps;
    __syncthreads();
    float off = 0.f, Tt = 0.f;
#pragma unroll
    for (int w2 = 0; w2 < 8; w2++) {
      float rw = sh_red[w2];
      if (w2 < wv) off += rw;
      Tt += rw;
    }
    float S = ps + off;  // inclusive prefix over block (desc sorted)
    float asum = 2.f * S - Tt + (float)(N - 2 - 2 * t) * sv;
    sh_Uu[PAD + t] = -asum * L2T;
  }
  __syncthreads();

  // band geometry (float4-aligned, covers [t-W, t+W])
  const int base = (t & ~3) - W;  // PAD+base >= 32, multiple of 4
  const float vi = 511.f - 2.f * (float)t;

  float4 Krow[NCH], Kcol[NCH];
  float rt = 1.f, ct;

  // ---- init row softmax: build Krow (linear, row-stochastic) + rl0 ----
  {
    float e0 = fmaf(vi, sh_Qs[PAD + t - 1], sh_Uu[PAD + t - 1]);
    float e1 = fmaf(vi, sh_Qs[PAD + t], sh_Uu[PAD + t]);
    float e2 = fmaf(vi, sh_Qs[PAD + t + 1], sh_Uu[PAD + t + 1]);
    float em = -fmaxf(e1, fmaxf(e0, e2));
    const float4* q4 = (const float4*)(sh_Qs + PAD + base);
    const float4* u4 = (const float4*)(sh_Uu + PAD + base);
    float z0 = 0.f, z1 = 0.f, z2 = 0.f, z3 = 0.f;
#pragma unroll
    for (int c = 0; c < NCH; c++) {
      float4 a = q4[c], cc = u4[c];
      float t0 = EXP2F(fmaf(vi, a.x, cc.x) + em);
      float t1 = EXP2F(fmaf(vi, a.y, cc.y) + em);
      float t2 = EXP2F(fmaf(vi, a.z, cc.z) + em);
      float t3 = EXP2F(fmaf(vi, a.w, cc.w) + em);
      Krow[c].x = t0; Krow[c].y = t1; Krow[c].z = t2; Krow[c].w = t3;
      z0 += t0; z1 += t1; z2 += t2; z3 += t3;
    }
    float Z = (z0 + z2) + (z1 + z3);
    float invZ = 1.f / Z;
    sh_Rl[PAD + t] = em - LOG2F(Z);
#pragma unroll
    for (int c = 0; c < NCH; c++) {
      Krow[c].x *= invZ; Krow[c].y *= invZ;
      Krow[c].z *= invZ; Krow[c].w *= invZ;
    }
  }
  __syncthreads();

  // ---- col pass 1 (log-domain, builds Kcol) -> linear c ----
  {
    const float qsr = sh_Qs[PAD + t];
    const float c0 = sh_Uu[PAD + t];
    const float4* r4 = (const float4*)(sh_Rl + PAD + base);
    float a0 = 0.f, a1 = 0.f, a2 = 0.f, a3 = 0.f;
    float v = 511.f - 2.f * (float)base;
#pragma unroll
    for (int c = 0; c < NCH; c++) {
      float4 r = r4[c];
      float t0 = EXP2F(fmaf(v, qsr, c0) + r.x); v -= 2.f;
      float t1 = EXP2F(fmaf(v, qsr, c0) + r.y); v -= 2.f;
      float t2 = EXP2F(fmaf(v, qsr, c0) + r.z); v -= 2.f;
      float t3 = EXP2F(fmaf(v, qsr, c0) + r.w); v -= 2.f;
      Kcol[c].x = t0; Kcol[c].y = t1; Kcol[c].z = t2; Kcol[c].w = t3;
      a0 += t0; a1 += t1; a2 += t2; a3 += t3;
    }
    float A = (a0 + a2) + (a1 + a3);  // true col sum (r=1, c=1)
    ct = 1.f / fmaxf(A, 1e-10f);
    sh_c[PAD + t] = ct;
  }
  __syncthreads();

  // ---- linear Sinkhorn: row1..row5, col2..col5 (fma-only passes) ----
#pragma unroll 1
  for (int it = 0; it < 5; it++) {
    {  // row pass: A = sum Krow * c-band
      const float4* c4 = (const float4*)(sh_c + PAD + base);
      float a0 = 0.f, a1 = 0.f, a2 = 0.f, a3 = 0.f;
#pragma unroll
      for (int c = 0; c < NCH; c++) {
        float4 cc = c4[c];
        a0 = fmaf(Krow[c].x, cc.x, a0);
        a1 = fmaf(Krow[c].y, cc.y, a1);
        a2 = fmaf(Krow[c].z, cc.z, a2);
        a3 = fmaf(Krow[c].w, cc.w, a3);
      }
      float A = (a0 + a2) + (a1 + a3);
      float trues = rt * A;  // true row sum of current matrix
      rt = rt / fmaxf(trues, 1e-10f);
      sh_r[PAD + t] = rt;
      if (it == 4) {  // final state: prep tail arrays
        if (which)
          sh_lw[PAD + t] = (float)(N - t) * rt;          // wr for approx_rank
        else
          sh_lw[PAD + t] = sh_Uu[PAD + t] + LOG2F(ct);   // fin = u0 + log2(c)
      }
    }
    __syncthreads();
    if (it < 4) {
      {  // col pass: A = sum Kcol * r-band
        const float4* r4 = (const float4*)(sh_r + PAD + base);
        float a0 = 0.f, a1 = 0.f, a2 = 0.f, a3 = 0.f;
#pragma unroll
        for (int c = 0; c < NCH; c++) {
          float4 rr = r4[c];
          a0 = fmaf(Kcol[c].x, rr.x, a0);
          a1 = fmaf(Kcol[c].y, rr.y, a1);
          a2 = fmaf(Kcol[c].z, rr.z, a2);
          a3 = fmaf(Kcol[c].w, rr.w, a3);
        }
        float A = (a0 + a2) + (a1 + a3);
        float trues = ct * A;  // true col sum of current matrix
        ct = ct / fmaxf(trues, 1e-10f);
        sh_c[PAD + t] = ct;
      }
      __syncthreads();
    }
  }

  if (which == 0) {
    // ===================== NDCG path =====================
    // wave-per-row approx_rel: P[r][j] = exp2(cv*qs_j + fin_j + rl0_r) * r_r
#pragma unroll
    for (int r = wv; r < TOPK; r += 8) {
      const float cv = 511.f - 2.f * (float)r;
      const float rl = sh_Rl[PAD + r];
      const float rr = sh_r[PAD + r];
      const int rbase = (r & ~3) - W;
      float srel = 0.f;
#pragma unroll
      for (int k = 0; k < 2; k++) {
        int e = ln + 64 * k;
        if (e < BAND) {
          int j = rbase + e;
          float ex = fmaf(cv, sh_Qs[PAD + j], sh_lw[PAD + j]) + rl;
          float rv2 = ((unsigned)j < N) ? sh_relS[j] : 0.f;
          srel = fmaf(EXP2F(ex), rv2, srel);
        }
      }
#pragma unroll
      for (int mm = 32; mm >= 1; mm >>= 1) srel += __shfl_xor(srel, mm, 64);
      if (ln == 0) sh_row[r] = srel * rr;
    }
    // dcg contrib: sorted position t holds the item at descending rank t
    float cd = (t < TOPK) ? (EXP2F(sh_relS[t]) - 1.f) * sh_invd[t] : 0.f;
    // bdcg: rank from fused loop (rnk2), rel value still in register
    float cb = 0.f;
    if (rnk2 < TOPK) cb = (EXP2F(rv) - 1.f) * sh_invd[rnk2];
    // dual interleaved wave reduce (dcg, bdcg)
#pragma unroll
    for (int mm = 32; mm >= 1; mm >>= 1) {
      cd += __shfl_xor(cd, mm, 64);
      cb += __shfl_xor(cb, mm, 64);
    }
    if (ln == 0) { sh_w1[wv] = cd; sh_w2[wv] = cb; }
    __syncthreads();
    if (t == 0) {
      float adcg = 0.f;
#pragma unroll
      for (int r = 0; r < TOPK; r++)
        adcg += (EXP2F(sh_row[r]) - 1.f) * sh_invd[r];
      float dcg = 0.f, bdcg = 0.f;
#pragma unroll
      for (int w2 = 0; w2 < 8; w2++) { dcg += sh_w1[w2]; bdcg += sh_w2[w2]; }
      out[u] = adcg / bdcg;
      out[U_CNT + u] = dcg / bdcg;
    }
  } else {
    // ===================== Diversity path =====================
    {  // approx_rank: ar_t = ct * sum_i Kcol[i] * wr[i]  (fma-only)
      const float4* l4 = (const float4*)(sh_lw + PAD + base);
      float a0 = 0.f, a1 = 0.f, a2 = 0.f, a3 = 0.f;
#pragma unroll
      for (int c = 0; c < NCH; c++) {
        float4 r = l4[c];
        a0 = fmaf(Kcol[c].x, r.x, a0);
        a1 = fmaf(Kcol[c].y, r.y, a1);
        a2 = fmaf(Kcol[c].z, r.z, a2);
        a3 = fmaf(Kcol[c].w, r.w, a3);
      }
      float ar = ct * ((a0 + a2) + (a1 + a3));
      float arj_s = 1.f / (1.f + EXP2F((502.f - ar) * LOG2E));  // sigmoid
      int o = sh_pos[t];
      sh_aux[o] = arj_s;                  // scatter to orig item index
      sh_rr[o] = (t < TOPK) ? 1.f : 0.f;  // desc rank < 10 -> top-10
    }
    float inv = 1.f / fmaxf(sqrtf(ssq), 1e-8f);  // orig item t (early ssq)
    sh_inv[t] = inv;
    float om = 1.f - ssq * inv * inv;  // 1 - ||n||^2 for ORIG item t
    __syncthreads();
    float arj = sh_aux[t], rrj = sh_rr[t];
    float r1 = arj, r2 = arj * arj, r3 = arj * arj * om, r4v = rrj,
          r5v = rrj * om;
#pragma unroll
    for (int mm = 32; mm >= 1; mm >>= 1) {
      r1 += __shfl_xor(r1, mm, 64);
      r2 += __shfl_xor(r2, mm, 64);
      r3 += __shfl_xor(r3, mm, 64);
      r4v += __shfl_xor(r4v, mm, 64);
      r5v += __shfl_xor(r5v, mm, 64);
    }
    if (ln == 0) {
      sh_w1[wv] = r1; sh_w2[wv] = r2; sh_w3[wv] = r3;
      sh_w4[wv] = r4v; sh_w5[wv] = r5v;
    }
    // V = sum_j a_j * n_j (64-dim): wave wv handles 64 j's, lane = feature
    const float* bu = batch + (size_t)u * N * F_STRIDE;
    float va = 0.f, vr = 0.f;
#pragma unroll 8
    for (int jj = 0; jj < 64; jj++) {
      int j2 = (wv << 6) + jj;
      float x = bu[(size_t)j2 * F_STRIDE + ln] * sh_inv[j2];
      va = fmaf(sh_aux[j2], x, va);
      vr = fmaf(sh_rr[j2], x, vr);
    }
    sh_pA[t] = va;
    sh_pB[t] = vr;
    __syncthreads();
    float qa = 0.f, qr = 0.f;
    if (t < 64) {
      float VA = 0.f, VR = 0.f;
#pragma unroll
      for (int c2 = 0; c2 < 8; c2++) {
        VA += sh_pA[c2 * 64 + t];
        VR += sh_pB[c2 * 64 + t];
      }
      qa = VA * VA;
      qr = VR * VR;
    }
#pragma unroll
    for (int mm = 32; mm >= 1; mm >>= 1) {
      qa += __shfl_xor(qa, mm, 64);
      qr += __shfl_xor(qr, mm, 64);
    }
    if (t == 0) {  // qa/qr complete in wave 0; sh_w* visible since last bar
      float S1a = 0.f, S2a = 0.f, DA = 0.f, S1r = 0.f, DR = 0.f;
#pragma unroll
      for (int w2 = 0; w2 < 8; w2++) {
        S1a += sh_w1[w2]; S2a += sh_w2[w2]; DA += sh_w3[w2];
        S1r += sh_w4[w2]; DR += sh_w5[w2];
      }
      // sum_{i<j} a_i a_j (1 - n_i.n_j) = 0.5*(S1^2 - ||V||^2 - diag)
      float numA = 0.5f * (S1a * S1a - qa - DA);
      float denA = 0.5f * (S1a * S1a - S2a);
      out[2 * U_CNT + u] = numA / denA;
      float numR = 0.5f * (S1r * S1r - qr - DR);
      float denR = 0.5f * (S1r * S1r - S1r);
      out[3 * U_CNT + u] = numR / denR;
    }
  }
}

extern "C" void kernel_launch(void* const* d_in, const int* in_sizes, int n_in,
                              void* d_out, int out_size, void* d_ws,
                              size_t ws_size, hipStream_t stream) {
  (void)in_sizes; (void)n_in; (void)d_ws; (void)ws_size; (void)out_size;
  const float* batch = (const float*)d_in[0];
  const float* sdiv = (const float*)d_in[1];
  const float* sndcg = (const float*)d_in[2];
  const float* rel = (const float*)d_in[3];
  float* out = (float*)d_out;
  loss_kernel<<<dim3(U_CNT * 2), dim3(N), 0, stream>>>(batch, sdiv, sndcg, rel,
                                                       out);
}

// Round 15
// 24.236 us; speedup vs baseline: 1.4913x; 1.1581x over previous
//
#include <hip/hip_runtime.h>

#define N 512
#define U_CNT 128
#define F_STRIDE 80
#define TOPK 10
#define W 32                  // half band width (sorted space)
#define PAD 64
#define BSZ (PAD + N + PAD)   // 640
#define NCH ((2 * W + 4) / 4) // 17 band float4 chunks
#define BAND (2 * W + 4)      // 68
// log2(e)/tau with tau = 0.1
#define L2T 14.426950408889634f
#define LOG2E 1.4426950408889634f
#define NEGBIG -1.0e30f

#if defined(__has_builtin)
#if __has_builtin(__builtin_amdgcn_exp2f)
#define EXP2F(x) __builtin_amdgcn_exp2f(x)
#endif
#if __has_builtin(__builtin_amdgcn_logf)
#define LOG2F(x) __builtin_amdgcn_logf(x)
#endif
#endif
#ifndef EXP2F
#define EXP2F(x) exp2f(x)
#endif
#ifndef LOG2F
#define LOG2F(x) log2f(x)
#endif

// monotone sortable key: ascending key order == descending value order,
// ties broken by smaller idx first (stable, matches jnp.argsort on -score)
__device__ __forceinline__ unsigned long long sortkey(float x, int idx) {
  unsigned int bb = __float_as_uint(x);
  bb ^= (unsigned int)((int)bb >> 31) | 0x80000000u;
  return ((unsigned long long)(~bb) << 10) | (unsigned long long)idx;
}

// One block per (user, which), 512 threads. Thread t owns sorted row/col t.
// LINEAR-domain banded Sinkhorn: P = diag(r) * P0 * diag(c), with thread t's
// kernel bands Krow[j]=P0[t][j], Kcol[i]=P0[i][t] cached in VGPRs. Each pass
// after col-1: 17 ds_read_b128 + 68 fma. Ranking via 256-bucket histogram
// (monotone value bucketing) + exact u64-key count inside tiny segments —
// bit-identical ranks at ~1/20 the VALU of full counting (r13 lesson: the
// O(N^2) count loop was ~8-10us of the 28us total).
__global__ __launch_bounds__(512, 2) void loss_kernel(
    const float* __restrict__ batch, const float* __restrict__ sdiv,
    const float* __restrict__ sndcg, const float* __restrict__ rel,
    float* __restrict__ out) {
  __shared__ __align__(16) unsigned long long bkA[N];  // bucketed score keys
  __shared__ __align__(16) unsigned long long bkB[N];  // bucketed rel keys
  __shared__ __align__(16) int sh_hist[2][256];
  __shared__ __align__(16) int sh_cur[2][256];
  __shared__ __align__(16) int sh_offs[2][257];
  __shared__ int sh_wt[8];
  __shared__ __align__(16) float sh_sv[N];    // sorted raw score
  __shared__ __align__(16) int sh_pos[N];     // rank -> orig index
  __shared__ __align__(16) float sh_Qs[BSZ];  // sorted qs (pad 0)
  __shared__ __align__(16) float sh_Uu[BSZ];  // u0 log col init (pad -1e30)
  __shared__ __align__(16) float sh_Rl[BSZ];  // rl0 log row init (pad -1e30)
  __shared__ __align__(16) float sh_r[BSZ];   // linear row scale (pad 0)
  __shared__ __align__(16) float sh_c[BSZ];   // linear col scale (pad 0)
  __shared__ __align__(16) float sh_lw[BSZ];  // fin=u0+log2(c) | wr=(N-i)*r
  __shared__ __align__(16) float sh_relS[N];  // rel sorted by score rank
  __shared__ __align__(16) float sh_aux[N];   // arj orig (div)
  __shared__ __align__(16) float sh_inv[N];
  __shared__ __align__(16) float sh_rr[N];
  __shared__ __align__(16) float sh_pA[N];
  __shared__ __align__(16) float sh_pB[N];
  __shared__ float sh_red[8];
  __shared__ float sh_w1[8], sh_w2[8], sh_w3[8], sh_w4[8], sh_w5[8];
  __shared__ float sh_row[TOPK];
  __shared__ float sh_invd[16];  // 1/log2(r+2), r<16

  const int b = blockIdx.x;
  const int u = b >> 1;
  const int which = b & 1;
  const int t = threadIdx.x;
  const int wv = t >> 6;
  const int ln = t & 63;

  // pad init (log sentinels NEGBIG; linear sentinels 0) + discount table
  if (t < PAD) {
    sh_Qs[t] = 0.f; sh_Uu[t] = NEGBIG; sh_Rl[t] = NEGBIG;
    sh_r[t] = 0.f; sh_c[t] = 0.f;
    sh_lw[t] = which ? 0.f : NEGBIG;
    if (t < 16) sh_invd[t] = 1.f / LOG2F((float)(t + 2));
  } else if (t < 2 * PAD) {
    int p = N + t;  // PAD + N + (t - PAD)
    sh_Qs[p] = 0.f; sh_Uu[p] = NEGBIG; sh_Rl[p] = NEGBIG;
    sh_r[p] = 0.f; sh_c[p] = 0.f;
    sh_lw[p] = which ? 0.f : NEGBIG;
  }
  // zero histograms + cursors
  {
    int half = t >> 8, tt = t & 255;
    sh_hist[half][tt] = 0;
    sh_cur[half][tt] = 0;
  }

  const float sj = ((which ? sdiv : sndcg) + (size_t)u * N)[t];
  const unsigned long long myk = sortkey(sj, t);
  int bA = (int)fmaf(sj, 32.f, 128.f);
  bA = min(max(bA, 0), 255);  // monotone bucket for N(0,1) scores
  float rv = 0.f;
  unsigned long long myk2 = 0;
  int bB = 0;
  if (!which) {
    rv = rel[(size_t)u * N + t];
    myk2 = sortkey(rv, t);
    bB = min(max((int)(rv * 256.f), 0), 255);  // monotone bucket for U[0,1)
  }
  float ssq = 0.f;
  if (which) {  // early item-norm: global latency hides under radix phases
    const float4* it4 =
        (const float4*)(batch + (size_t)(u * N + t) * F_STRIDE);
#pragma unroll
    for (int f4 = 0; f4 < 16; f4++) {
      float4 p = it4[f4];
      ssq = fmaf(p.x, p.x, ssq); ssq = fmaf(p.y, p.y, ssq);
      ssq = fmaf(p.z, p.z, ssq); ssq = fmaf(p.w, p.w, ssq);
    }
  }
  __syncthreads();

  // ---- histogram ----
  atomicAdd(&sh_hist[0][bA], 1);
  if (!which) atomicAdd(&sh_hist[1][bB], 1);
  __syncthreads();

  // ---- parallel 256-wide exclusive prefix (halves: waves 0-3 A, 4-7 B) ----
  {
    int half = t >> 8, tt = t & 255;
    int h = 0, ps = 0;
    bool act = (half == 0) || (!which);
    if (act) {
      h = sh_hist[half][tt];
      ps = h;
#pragma unroll
      for (int m = 1; m <= 32; m <<= 1) {
        int o = __shfl_up(ps, m, 64);
        if (ln >= m) ps += o;
      }
      if (ln == 63) sh_wt[(tt >> 6) | (half << 2)] = ps;
    }
    __syncthreads();
    if (act) {
      int w0 = (tt >> 6) | (half << 2);
      int off = 0;
#pragma unroll
      for (int w2 = 0; w2 < 4; w2++) {
        int wi = (half << 2) + w2;
        if (wi < w0) off += sh_wt[wi];
      }
      int ex = ps - h + off;  // exclusive prefix
      sh_offs[half][tt] = ex;
      if (tt == 255) sh_offs[half][256] = ex + h;  // == N
    }
  }
  __syncthreads();

  // ---- scatter keys into bucket segments ----
  {
    int sA = sh_offs[0][bA] + atomicAdd(&sh_cur[0][bA], 1);
    bkA[sA] = myk;
    if (!which) {
      int sB = sh_offs[1][bB] + atomicAdd(&sh_cur[1][bB], 1);
      bkB[sB] = myk2;
    }
  }
  __syncthreads();

  // ---- exact rank from tiny segment (bit-identical to full counting) ----
  int rnk2 = 0;
  {
    int lo = sh_offs[0][bA], hi = sh_offs[0][bA + 1];
    int rnk = N - hi;  // all higher buckets hold larger values
    for (int k = lo; k < hi; k++) rnk += (bkA[k] < myk);
    sh_sv[rnk] = sj;
    sh_pos[rnk] = t;
    if (!which) {
      sh_relS[rnk] = rv;  // direct scatter
      int lo2 = sh_offs[1][bB], hi2 = sh_offs[1][bB + 1];
      rnk2 = N - hi2;
      for (int k = lo2; k < hi2; k++) rnk2 += (bkB[k] < myk2);
    }
  }
  __syncthreads();

  // ---- sorted-space setup: Qs, asum via prefix scan -> u0 ----
  const float sv = sh_sv[t];
  sh_Qs[PAD + t] = sv * L2T;
  {
    float ps = sv;  // inclusive wave scan
#pragma unroll
    for (int m = 1; m <= 32; m <<= 1) {
      float o = __shfl_up(ps, m, 64);
      if (ln >= m) ps += o;
    }
    if (ln == 63) sh_red[wv] = ps;
    __syncthreads();
    float off = 0.f, Tt = 0.f;
#pragma unroll
    for (int w2 = 0; w2 < 8; w2++) {
      float rw = sh_red[w2];
      if (w2 < wv) off += rw;
      Tt += rw;
    }
    float S = ps + off;  // inclusive prefix over block (desc sorted)
    float asum = 2.f * S - Tt + (float)(N - 2 - 2 * t) * sv;
    sh_Uu[PAD + t] = -asum * L2T;
  }
  __syncthreads();

  // band geometry (float4-aligned, covers [t-W, t+W])
  const int base = (t & ~3) - W;  // PAD+base >= 32, multiple of 4
  const float vi = 511.f - 2.f * (float)t;

  float4 Krow[NCH], Kcol[NCH];
  float rt = 1.f, ct;

  // ---- init row softmax: build Krow (linear, row-stochastic) + rl0 ----
  {
    float e0 = fmaf(vi, sh_Qs[PAD + t - 1], sh_Uu[PAD + t - 1]);
    float e1 = fmaf(vi, sh_Qs[PAD + t], sh_Uu[PAD + t]);
    float e2 = fmaf(vi, sh_Qs[PAD + t + 1], sh_Uu[PAD + t + 1]);
    float em = -fmaxf(e1, fmaxf(e0, e2));
    const float4* q4 = (const float4*)(sh_Qs + PAD + base);
    const float4* u4 = (const float4*)(sh_Uu + PAD + base);
    float z0 = 0.f, z1 = 0.f, z2 = 0.f, z3 = 0.f;
#pragma unroll
    for (int c = 0; c < NCH; c++) {
      float4 a = q4[c], cc = u4[c];
      float t0 = EXP2F(fmaf(vi, a.x, cc.x) + em);
      float t1 = EXP2F(fmaf(vi, a.y, cc.y) + em);
      float t2 = EXP2F(fmaf(vi, a.z, cc.z) + em);
      float t3 = EXP2F(fmaf(vi, a.w, cc.w) + em);
      Krow[c].x = t0; Krow[c].y = t1; Krow[c].z = t2; Krow[c].w = t3;
      z0 += t0; z1 += t1; z2 += t2; z3 += t3;
    }
    float Z = (z0 + z2) + (z1 + z3);
    float invZ = 1.f / Z;
    sh_Rl[PAD + t] = em - LOG2F(Z);
#pragma unroll
    for (int c = 0; c < NCH; c++) {
      Krow[c].x *= invZ; Krow[c].y *= invZ;
      Krow[c].z *= invZ; Krow[c].w *= invZ;
    }
  }
  __syncthreads();

  // ---- col pass 1 (log-domain, builds Kcol) -> linear c ----
  {
    const float qsr = sh_Qs[PAD + t];
    const float c0 = sh_Uu[PAD + t];
    const float4* r4 = (const float4*)(sh_Rl + PAD + base);
    float a0 = 0.f, a1 = 0.f, a2 = 0.f, a3 = 0.f;
    float v = 511.f - 2.f * (float)base;
#pragma unroll
    for (int c = 0; c < NCH; c++) {
      float4 r = r4[c];
      float t0 = EXP2F(fmaf(v, qsr, c0) + r.x); v -= 2.f;
      float t1 = EXP2F(fmaf(v, qsr, c0) + r.y); v -= 2.f;
      float t2 = EXP2F(fmaf(v, qsr, c0) + r.z); v -= 2.f;
      float t3 = EXP2F(fmaf(v, qsr, c0) + r.w); v -= 2.f;
      Kcol[c].x = t0; Kcol[c].y = t1; Kcol[c].z = t2; Kcol[c].w = t3;
      a0 += t0; a1 += t1; a2 += t2; a3 += t3;
    }
    float A = (a0 + a2) + (a1 + a3);  // true col sum (r=1, c=1)
    ct = 1.f / fmaxf(A, 1e-10f);
    sh_c[PAD + t] = ct;
  }
  __syncthreads();

  // ---- linear Sinkhorn: row1..row5, col2..col5 (fma-only passes) ----
#pragma unroll 1
  for (int it = 0; it < 5; it++) {
    {  // row pass: A = sum Krow * c-band
      const float4* c4 = (const float4*)(sh_c + PAD + base);
      float a0 = 0.f, a1 = 0.f, a2 = 0.f, a3 = 0.f;
#pragma unroll
      for (int c = 0; c < NCH; c++) {
        float4 cc = c4[c];
        a0 = fmaf(Krow[c].x, cc.x, a0);
        a1 = fmaf(Krow[c].y, cc.y, a1);
        a2 = fmaf(Krow[c].z, cc.z, a2);
        a3 = fmaf(Krow[c].w, cc.w, a3);
      }
      float A = (a0 + a2) + (a1 + a3);
      float trues = rt * A;  // true row sum of current matrix
      rt = rt / fmaxf(trues, 1e-10f);
      sh_r[PAD + t] = rt;
      if (it == 4) {  // final state: prep tail arrays
        if (which)
          sh_lw[PAD + t] = (float)(N - t) * rt;          // wr for approx_rank
        else
          sh_lw[PAD + t] = sh_Uu[PAD + t] + LOG2F(ct);   // fin = u0 + log2(c)
      }
    }
    __syncthreads();
    if (it < 4) {
      {  // col pass: A = sum Kcol * r-band
        const float4* r4 = (const float4*)(sh_r + PAD + base);
        float a0 = 0.f, a1 = 0.f, a2 = 0.f, a3 = 0.f;
#pragma unroll
        for (int c = 0; c < NCH; c++) {
          float4 rr = r4[c];
          a0 = fmaf(Kcol[c].x, rr.x, a0);
          a1 = fmaf(Kcol[c].y, rr.y, a1);
          a2 = fmaf(Kcol[c].z, rr.z, a2);
          a3 = fmaf(Kcol[c].w, rr.w, a3);
        }
        float A = (a0 + a2) + (a1 + a3);
        float trues = ct * A;  // true col sum of current matrix
        ct = ct / fmaxf(trues, 1e-10f);
        sh_c[PAD + t] = ct;
      }
      __syncthreads();
    }
  }

  if (which == 0) {
    // ===================== NDCG path =====================
    // wave-per-row approx_rel: P[r][j] = exp2(cv*qs_j + fin_j + rl0_r) * r_r
#pragma unroll
    for (int r = wv; r < TOPK; r += 8) {
      const float cv = 511.f - 2.f * (float)r;
      const float rl = sh_Rl[PAD + r];
      const float rr = sh_r[PAD + r];
      const int rbase = (r & ~3) - W;
      float srel = 0.f;
#pragma unroll
      for (int k = 0; k < 2; k++) {
        int e = ln + 64 * k;
        if (e < BAND) {
          int j = rbase + e;
          float ex = fmaf(cv, sh_Qs[PAD + j], sh_lw[PAD + j]) + rl;
          float rv2 = ((unsigned)j < N) ? sh_relS[j] : 0.f;
          srel = fmaf(EXP2F(ex), rv2, srel);
        }
      }
#pragma unroll
      for (int mm = 32; mm >= 1; mm >>= 1) srel += __shfl_xor(srel, mm, 64);
      if (ln == 0) sh_row[r] = srel * rr;
    }
    // dcg contrib: sorted position t holds the item at descending rank t
    float cd = (t < TOPK) ? (EXP2F(sh_relS[t]) - 1.f) * sh_invd[t] : 0.f;
    // bdcg: rank from radix pass (rnk2), rel value still in register
    float cb = 0.f;
    if (rnk2 < TOPK) cb = (EXP2F(rv) - 1.f) * sh_invd[rnk2];
    // dual interleaved wave reduce (dcg, bdcg)
#pragma unroll
    for (int mm = 32; mm >= 1; mm >>= 1) {
      cd += __shfl_xor(cd, mm, 64);
      cb += __shfl_xor(cb, mm, 64);
    }
    if (ln == 0) { sh_w1[wv] = cd; sh_w2[wv] = cb; }
    __syncthreads();
    if (t == 0) {
      float adcg = 0.f;
#pragma unroll
      for (int r = 0; r < TOPK; r++)
        adcg += (EXP2F(sh_row[r]) - 1.f) * sh_invd[r];
      float dcg = 0.f, bdcg = 0.f;
#pragma unroll
      for (int w2 = 0; w2 < 8; w2++) { dcg += sh_w1[w2]; bdcg += sh_w2[w2]; }
      out[u] = adcg / bdcg;
      out[U_CNT + u] = dcg / bdcg;
    }
  } else {
    // ===================== Diversity path =====================
    {  // approx_rank: ar_t = ct * sum_i Kcol[i] * wr[i]  (fma-only)
      const float4* l4 = (const float4*)(sh_lw + PAD + base);
      float a0 = 0.f, a1 = 0.f, a2 = 0.f, a3 = 0.f;
#pragma unroll
      for (int c = 0; c < NCH; c++) {
        float4 r = l4[c];
        a0 = fmaf(Kcol[c].x, r.x, a0);
        a1 = fmaf(Kcol[c].y, r.y, a1);
        a2 = fmaf(Kcol[c].z, r.z, a2);
        a3 = fmaf(Kcol[c].w, r.w, a3);
      }
      float ar = ct * ((a0 + a2) + (a1 + a3));
      float arj_s = 1.f / (1.f + EXP2F((502.f - ar) * LOG2E));  // sigmoid
      int o = sh_pos[t];
      sh_aux[o] = arj_s;                  // scatter to orig item index
      sh_rr[o] = (t < TOPK) ? 1.f : 0.f;  // desc rank < 10 -> top-10
    }
    float inv = 1.f / fmaxf(sqrtf(ssq), 1e-8f);  // orig item t (early ssq)
    sh_inv[t] = inv;
    float om = 1.f - ssq * inv * inv;  // 1 - ||n||^2 for ORIG item t
    __syncthreads();
    float arj = sh_aux[t], rrj = sh_rr[t];
    float r1 = arj, r2 = arj * arj, r3 = arj * arj * om, r4v = rrj,
          r5v = rrj * om;
#pragma unroll
    for (int mm = 32; mm >= 1; mm >>= 1) {
      r1 += __shfl_xor(r1, mm, 64);
      r2 += __shfl_xor(r2, mm, 64);
      r3 += __shfl_xor(r3, mm, 64);
      r4v += __shfl_xor(r4v, mm, 64);
      r5v += __shfl_xor(r5v, mm, 64);
    }
    if (ln == 0) {
      sh_w1[wv] = r1; sh_w2[wv] = r2; sh_w3[wv] = r3;
      sh_w4[wv] = r4v; sh_w5[wv] = r5v;
    }
    // V = sum_j a_j * n_j (64-dim): wave wv handles 64 j's, lane = feature
    const float* bu = batch + (size_t)u * N * F_STRIDE;
    float va = 0.f, vr = 0.f;
#pragma unroll 8
    for (int jj = 0; jj < 64; jj++) {
      int j2 = (wv << 6) + jj;
      float x = bu[(size_t)j2 * F_STRIDE + ln] * sh_inv[j2];
      va = fmaf(sh_aux[j2], x, va);
      vr = fmaf(sh_rr[j2], x, vr);
    }
    sh_pA[t] = va;
    sh_pB[t] = vr;
    __syncthreads();
    float qa = 0.f, qr = 0.f;
    if (t < 64) {
      float VA = 0.f, VR = 0.f;
#pragma unroll
      for (int c2 = 0; c2 < 8; c2++) {
        VA += sh_pA[c2 * 64 + t];
        VR += sh_pB[c2 * 64 + t];
      }
      qa = VA * VA;
      qr = VR * VR;
    }
#pragma unroll
    for (int mm = 32; mm >= 1; mm >>= 1) {
      qa += __shfl_xor(qa, mm, 64);
      qr += __shfl_xor(qr, mm, 64);
    }
    if (t == 0) {  // qa/qr complete in wave 0; sh_w* visible since last bar
      float S1a = 0.f, S2a = 0.f, DA = 0.f, S1r = 0.f, DR = 0.f;
#pragma unroll
      for (int w2 = 0; w2 < 8; w2++) {
        S1a += sh_w1[w2]; S2a += sh_w2[w2]; DA += sh_w3[w2];
        S1r += sh_w4[w2]; DR += sh_w5[w2];
      }
      // sum_{i<j} a_i a_j (1 - n_i.n_j) = 0.5*(S1^2 - ||V||^2 - diag)
      float numA = 0.5f * (S1a * S1a - qa - DA);
      float denA = 0.5f * (S1a * S1a - S2a);
      out[2 * U_CNT + u] = numA / denA;
      float numR = 0.5f * (S1r * S1r - qr - DR);
      float denR = 0.5f * (S1r * S1r - S1r);
      out[3 * U_CNT + u] = numR / denR;
    }
  }
}

extern "C" void kernel_launch(void* const* d_in, const int* in_sizes, int n_in,
                              void* d_out, int out_size, void* d_ws,
                              size_t ws_size, hipStream_t stream) {
  (void)in_sizes; (void)n_in; (void)d_ws; (void)ws_size; (void)out_size;
  const float* batch = (const float*)d_in[0];
  const float* sdiv = (const float*)d_in[1];
  const float* sndcg = (const float*)d_in[2];
  const float* rel = (const float*)d_in[3];
  float* out = (float*)d_out;
  loss_kernel<<<dim3(U_CNT * 2), dim3(N), 0, stream>>>(batch, sdiv, sndcg, rel,
                                                       out);
}

// Round 16
// 21.778 us; speedup vs baseline: 1.6596x; 1.1129x over previous
//
#include <hip/hip_runtime.h>

#define N 512
#define U_CNT 128
#define F_STRIDE 80
#define TOPK 10
#define W 24                  // half band width (sorted space)
#define PAD 64
#define BSZ (PAD + N + PAD)   // 640
#define NCH ((2 * W + 4) / 4) // 13 band float4 chunks
#define BAND (2 * W + 4)      // 52
// log2(e)/tau with tau = 0.1
#define L2T 14.426950408889634f
#define LOG2E 1.4426950408889634f
#define NEGBIG -1.0e30f

#if defined(__has_builtin)
#if __has_builtin(__builtin_amdgcn_exp2f)
#define EXP2F(x) __builtin_amdgcn_exp2f(x)
#endif
#if __has_builtin(__builtin_amdgcn_logf)
#define LOG2F(x) __builtin_amdgcn_logf(x)
#endif
#endif
#ifndef EXP2F
#define EXP2F(x) exp2f(x)
#endif
#ifndef LOG2F
#define LOG2F(x) log2f(x)
#endif

// monotone sortable key: ascending key order == descending value order,
// ties broken by smaller idx first (stable, matches jnp.argsort on -score)
__device__ __forceinline__ unsigned long long sortkey(float x, int idx) {
  unsigned int bb = __float_as_uint(x);
  bb ^= (unsigned int)((int)bb >> 31) | 0x80000000u;
  return ((unsigned long long)(~bb) << 10) | (unsigned long long)idx;
}

// One block per (user, which), 512 threads. Thread t owns sorted row/col t.
// LINEAR-domain banded Sinkhorn: P = diag(r) * P0 * diag(c), with thread t's
// kernel bands Krow[j]=P0[t][j], Kcol[i]=P0[i][t] cached in VGPRs. Each pass
// after col-1: 13 ds_read_b128 + 52 fma. Ranking via 256-bucket histogram +
// exact u64-key count inside tiny segments (bit-identical ranks). Bucket
// prefix scan is fully intra-wave (lane owns 4 buckets) -> no mid barrier.
// W=24: worst-case band tail ~2^-13 relative to each sum's peak (typ 2^-40),
// output shift <=1e-4 vs 0.021 threshold; validated via absmax this round.
__global__ __launch_bounds__(512, 2) void loss_kernel(
    const float* __restrict__ batch, const float* __restrict__ sdiv,
    const float* __restrict__ sndcg, const float* __restrict__ rel,
    float* __restrict__ out) {
  __shared__ __align__(16) unsigned long long bkA[N];  // bucketed score keys
  __shared__ __align__(16) unsigned long long bkB[N];  // bucketed rel keys
  __shared__ __align__(16) int sh_hist[2][256];
  __shared__ __align__(16) int sh_cur[2][256];
  __shared__ __align__(16) int sh_offs[2][260];
  __shared__ __align__(16) float sh_sv[N];    // sorted raw score
  __shared__ __align__(16) int sh_pos[N];     // rank -> orig index
  __shared__ __align__(16) float sh_Qs[BSZ];  // sorted qs (pad 0)
  __shared__ __align__(16) float sh_Uu[BSZ];  // u0 log col init (pad -1e30)
  __shared__ __align__(16) float sh_Rl[BSZ];  // rl0 log row init (pad -1e30)
  __shared__ __align__(16) float sh_r[BSZ];   // linear row scale (pad 0)
  __shared__ __align__(16) float sh_c[BSZ];   // linear col scale (pad 0)
  __shared__ __align__(16) float sh_lw[BSZ];  // fin=u0+log2(c) | wr=(N-i)*r
  __shared__ __align__(16) float sh_relS[N];  // rel sorted by score rank
  __shared__ __align__(16) float sh_aux[N];   // arj orig (div)
  __shared__ __align__(16) float sh_inv[N];
  __shared__ __align__(16) float sh_rr[N];
  __shared__ __align__(16) float sh_pA[N];
  __shared__ __align__(16) float sh_pB[N];
  __shared__ float sh_red[8];
  __shared__ float sh_w1[8], sh_w2[8], sh_w3[8], sh_w4[8], sh_w5[8];
  __shared__ float sh_row[TOPK];
  __shared__ float sh_invd[16];  // 1/log2(r+2), r<16

  const int b = blockIdx.x;
  const int u = b >> 1;
  const int which = b & 1;
  const int t = threadIdx.x;
  const int wv = t >> 6;
  const int ln = t & 63;

  // pad init (log sentinels NEGBIG; linear sentinels 0) + discount table
  if (t < PAD) {
    sh_Qs[t] = 0.f; sh_Uu[t] = NEGBIG; sh_Rl[t] = NEGBIG;
    sh_r[t] = 0.f; sh_c[t] = 0.f;
    sh_lw[t] = which ? 0.f : NEGBIG;
    if (t < 16) sh_invd[t] = 1.f / LOG2F((float)(t + 2));
  } else if (t < 2 * PAD) {
    int p = N + t;  // PAD + N + (t - PAD)
    sh_Qs[p] = 0.f; sh_Uu[p] = NEGBIG; sh_Rl[p] = NEGBIG;
    sh_r[p] = 0.f; sh_c[p] = 0.f;
    sh_lw[p] = which ? 0.f : NEGBIG;
  }
  // zero histograms + cursors
  {
    int half = t >> 8, tt = t & 255;
    sh_hist[half][tt] = 0;
    sh_cur[half][tt] = 0;
  }

  const float sj = ((which ? sdiv : sndcg) + (size_t)u * N)[t];
  const unsigned long long myk = sortkey(sj, t);
  int bA = (int)fmaf(sj, 32.f, 128.f);
  bA = min(max(bA, 0), 255);  // monotone bucket for N(0,1) scores
  float rv = 0.f;
  unsigned long long myk2 = 0;
  int bB = 0;
  if (!which) {
    rv = rel[(size_t)u * N + t];
    myk2 = sortkey(rv, t);
    bB = min(max((int)(rv * 256.f), 0), 255);  // monotone bucket for U[0,1)
  }
  float ssq = 0.f;
  if (which) {  // early item-norm: global latency hides under radix phases
    const float4* it4 =
        (const float4*)(batch + (size_t)(u * N + t) * F_STRIDE);
#pragma unroll
    for (int f4 = 0; f4 < 16; f4++) {
      float4 p = it4[f4];
      ssq = fmaf(p.x, p.x, ssq); ssq = fmaf(p.y, p.y, ssq);
      ssq = fmaf(p.z, p.z, ssq); ssq = fmaf(p.w, p.w, ssq);
    }
  }
  __syncthreads();

  // ---- histogram ----
  atomicAdd(&sh_hist[0][bA], 1);
  if (!which) atomicAdd(&sh_hist[1][bB], 1);
  __syncthreads();

  // ---- intra-wave 256-wide exclusive prefix: lane owns 4 buckets ----
  // wave 0 scans side A; wave 4 scans side B (ndcg only). No mid barrier.
  if (wv == 0 || (wv == 4 && !which)) {
    int half = wv >> 2;
    int4 h = ((const int4*)sh_hist[half])[ln];
    int hs = h.x + h.y + h.z + h.w;
    int ps = hs;
#pragma unroll
    for (int m = 1; m <= 32; m <<= 1) {
      int o = __shfl_up(ps, m, 64);
      if (ln >= m) ps += o;
    }
    int e0 = ps - hs;  // exclusive prefix of lane's first bucket
    int4 e;
    e.x = e0; e.y = e0 + h.x; e.z = e.y + h.y; e.w = e.z + h.z;
    ((int4*)sh_offs[half])[ln] = e;
    if (ln == 63) sh_offs[half][256] = ps;  // == N
  }
  __syncthreads();

  // ---- scatter keys into bucket segments ----
  {
    int sA = sh_offs[0][bA] + atomicAdd(&sh_cur[0][bA], 1);
    bkA[sA] = myk;
    if (!which) {
      int sB = sh_offs[1][bB] + atomicAdd(&sh_cur[1][bB], 1);
      bkB[sB] = myk2;
    }
  }
  __syncthreads();

  // ---- exact rank from tiny segment (bit-identical to full counting) ----
  int rnk2 = 0;
  {
    int lo = sh_offs[0][bA], hi = sh_offs[0][bA + 1];
    int rnk = N - hi;  // all higher buckets hold larger values
    for (int k = lo; k < hi; k++) rnk += (bkA[k] < myk);
    sh_sv[rnk] = sj;
    sh_pos[rnk] = t;
    if (!which) {
      sh_relS[rnk] = rv;  // direct scatter
      int lo2 = sh_offs[1][bB], hi2 = sh_offs[1][bB + 1];
      rnk2 = N - hi2;
      for (int k = lo2; k < hi2; k++) rnk2 += (bkB[k] < myk2);
    }
  }
  __syncthreads();

  // ---- sorted-space setup: Qs, asum via prefix scan -> u0 ----
  const float sv = sh_sv[t];
  sh_Qs[PAD + t] = sv * L2T;
  {
    float ps = sv;  // inclusive wave scan
#pragma unroll
    for (int m = 1; m <= 32; m <<= 1) {
      float o = __shfl_up(ps, m, 64);
      if (ln >= m) ps += o;
    }
    if (ln == 63) sh_red[wv] = ps;
    __syncthreads();
    float off = 0.f, Tt = 0.f;
#pragma unroll
    for (int w2 = 0; w2 < 8; w2++) {
      float rw = sh_red[w2];
      if (w2 < wv) off += rw;
      Tt += rw;
    }
    float S = ps + off;  // inclusive prefix over block (desc sorted)
    float asum = 2.f * S - Tt + (float)(N - 2 - 2 * t) * sv;
    sh_Uu[PAD + t] = -asum * L2T;
  }
  __syncthreads();

  // band geometry (float4-aligned, covers [t-W, t+W])
  const int base = (t & ~3) - W;  // PAD+base >= 40, multiple of 4
  const float vi = 511.f - 2.f * (float)t;

  float4 Krow[NCH], Kcol[NCH];
  float rt = 1.f, ct;

  // ---- init row softmax: build Krow (linear, row-stochastic) + rl0 ----
  {
    float e0 = fmaf(vi, sh_Qs[PAD + t - 1], sh_Uu[PAD + t - 1]);
    float e1 = fmaf(vi, sh_Qs[PAD + t], sh_Uu[PAD + t]);
    float e2 = fmaf(vi, sh_Qs[PAD + t + 1], sh_Uu[PAD + t + 1]);
    float em = -fmaxf(e1, fmaxf(e0, e2));
    const float4* q4 = (const float4*)(sh_Qs + PAD + base);
    const float4* u4 = (const float4*)(sh_Uu + PAD + base);
    float z0 = 0.f, z1 = 0.f, z2 = 0.f, z3 = 0.f;
#pragma unroll
    for (int c = 0; c < NCH; c++) {
      float4 a = q4[c], cc = u4[c];
      float t0 = EXP2F(fmaf(vi, a.x, cc.x) + em);
      float t1 = EXP2F(fmaf(vi, a.y, cc.y) + em);
      float t2 = EXP2F(fmaf(vi, a.z, cc.z) + em);
      float t3 = EXP2F(fmaf(vi, a.w, cc.w) + em);
      Krow[c].x = t0; Krow[c].y = t1; Krow[c].z = t2; Krow[c].w = t3;
      z0 += t0; z1 += t1; z2 += t2; z3 += t3;
    }
    float Z = (z0 + z2) + (z1 + z3);
    float invZ = 1.f / Z;
    sh_Rl[PAD + t] = em - LOG2F(Z);
#pragma unroll
    for (int c = 0; c < NCH; c++) {
      Krow[c].x *= invZ; Krow[c].y *= invZ;
      Krow[c].z *= invZ; Krow[c].w *= invZ;
    }
  }
  __syncthreads();

  // ---- col pass 1 (log-domain, builds Kcol) -> linear c ----
  {
    const float qsr = sh_Qs[PAD + t];
    const float c0 = sh_Uu[PAD + t];
    const float4* r4 = (const float4*)(sh_Rl + PAD + base);
    float a0 = 0.f, a1 = 0.f, a2 = 0.f, a3 = 0.f;
    float v = 511.f - 2.f * (float)base;
#pragma unroll
    for (int c = 0; c < NCH; c++) {
      float4 r = r4[c];
      float t0 = EXP2F(fmaf(v, qsr, c0) + r.x); v -= 2.f;
      float t1 = EXP2F(fmaf(v, qsr, c0) + r.y); v -= 2.f;
      float t2 = EXP2F(fmaf(v, qsr, c0) + r.z); v -= 2.f;
      float t3 = EXP2F(fmaf(v, qsr, c0) + r.w); v -= 2.f;
      Kcol[c].x = t0; Kcol[c].y = t1; Kcol[c].z = t2; Kcol[c].w = t3;
      a0 += t0; a1 += t1; a2 += t2; a3 += t3;
    }
    float A = (a0 + a2) + (a1 + a3);  // true col sum (r=1, c=1)
    ct = 1.f / fmaxf(A, 1e-10f);
    sh_c[PAD + t] = ct;
  }
  __syncthreads();

  // ---- linear Sinkhorn: row1..row5, col2..col5 (fma-only passes) ----
#pragma unroll 1
  for (int it = 0; it < 5; it++) {
    {  // row pass: A = sum Krow * c-band
      const float4* c4 = (const float4*)(sh_c + PAD + base);
      float a0 = 0.f, a1 = 0.f, a2 = 0.f, a3 = 0.f;
#pragma unroll
      for (int c = 0; c < NCH; c++) {
        float4 cc = c4[c];
        a0 = fmaf(Krow[c].x, cc.x, a0);
        a1 = fmaf(Krow[c].y, cc.y, a1);
        a2 = fmaf(Krow[c].z, cc.z, a2);
        a3 = fmaf(Krow[c].w, cc.w, a3);
      }
      float A = (a0 + a2) + (a1 + a3);
      float trues = rt * A;  // true row sum of current matrix
      rt = rt / fmaxf(trues, 1e-10f);
      sh_r[PAD + t] = rt;
      if (it == 4) {  // final state: prep tail arrays
        if (which)
          sh_lw[PAD + t] = (float)(N - t) * rt;          // wr for approx_rank
        else
          sh_lw[PAD + t] = sh_Uu[PAD + t] + LOG2F(ct);   // fin = u0 + log2(c)
      }
    }
    __syncthreads();
    if (it < 4) {
      {  // col pass: A = sum Kcol * r-band
        const float4* r4 = (const float4*)(sh_r + PAD + base);
        float a0 = 0.f, a1 = 0.f, a2 = 0.f, a3 = 0.f;
#pragma unroll
        for (int c = 0; c < NCH; c++) {
          float4 rr = r4[c];
          a0 = fmaf(Kcol[c].x, rr.x, a0);
          a1 = fmaf(Kcol[c].y, rr.y, a1);
          a2 = fmaf(Kcol[c].z, rr.z, a2);
          a3 = fmaf(Kcol[c].w, rr.w, a3);
        }
        float A = (a0 + a2) + (a1 + a3);
        float trues = ct * A;  // true col sum of current matrix
        ct = ct / fmaxf(trues, 1e-10f);
        sh_c[PAD + t] = ct;
      }
      __syncthreads();
    }
  }

  if (which == 0) {
    // ===================== NDCG path =====================
    // wave-per-row approx_rel: P[r][j] = exp2(cv*qs_j + fin_j + rl0_r) * r_r
#pragma unroll
    for (int r = wv; r < TOPK; r += 8) {
      const float cv = 511.f - 2.f * (float)r;
      const float rl = sh_Rl[PAD + r];
      const float rr = sh_r[PAD + r];
      const int rbase = (r & ~3) - W;
      float srel = 0.f;
      {
        int e = ln;  // BAND = 52 <= 64: single strip
        if (e < BAND) {
          int j = rbase + e;
          float ex = fmaf(cv, sh_Qs[PAD + j], sh_lw[PAD + j]) + rl;
          float rv2 = ((unsigned)j < N) ? sh_relS[j] : 0.f;
          srel = fmaf(EXP2F(ex), rv2, srel);
        }
      }
#pragma unroll
      for (int mm = 32; mm >= 1; mm >>= 1) srel += __shfl_xor(srel, mm, 64);
      if (ln == 0) sh_row[r] = srel * rr;
    }
    // dcg contrib: sorted position t holds the item at descending rank t
    float cd = (t < TOPK) ? (EXP2F(sh_relS[t]) - 1.f) * sh_invd[t] : 0.f;
    // bdcg: rank from radix pass (rnk2), rel value still in register
    float cb = 0.f;
    if (rnk2 < TOPK) cb = (EXP2F(rv) - 1.f) * sh_invd[rnk2];
    // dual interleaved wave reduce (dcg, bdcg)
#pragma unroll
    for (int mm = 32; mm >= 1; mm >>= 1) {
      cd += __shfl_xor(cd, mm, 64);
      cb += __shfl_xor(cb, mm, 64);
    }
    if (ln == 0) { sh_w1[wv] = cd; sh_w2[wv] = cb; }
    __syncthreads();
    if (t == 0) {
      float adcg = 0.f;
#pragma unroll
      for (int r = 0; r < TOPK; r++)
        adcg += (EXP2F(sh_row[r]) - 1.f) * sh_invd[r];
      float dcg = 0.f, bdcg = 0.f;
#pragma unroll
      for (int w2 = 0; w2 < 8; w2++) { dcg += sh_w1[w2]; bdcg += sh_w2[w2]; }
      out[u] = adcg / bdcg;
      out[U_CNT + u] = dcg / bdcg;
    }
  } else {
    // ===================== Diversity path =====================
    {  // approx_rank: ar_t = ct * sum_i Kcol[i] * wr[i]  (fma-only)
      const float4* l4 = (const float4*)(sh_lw + PAD + base);
      float a0 = 0.f, a1 = 0.f, a2 = 0.f, a3 = 0.f;
#pragma unroll
      for (int c = 0; c < NCH; c++) {
        float4 r = l4[c];
        a0 = fmaf(Kcol[c].x, r.x, a0);
        a1 = fmaf(Kcol[c].y, r.y, a1);
        a2 = fmaf(Kcol[c].z, r.z, a2);
        a3 = fmaf(Kcol[c].w, r.w, a3);
      }
      float ar = ct * ((a0 + a2) + (a1 + a3));
      float arj_s = 1.f / (1.f + EXP2F((502.f - ar) * LOG2E));  // sigmoid
      int o = sh_pos[t];
      sh_aux[o] = arj_s;                  // scatter to orig item index
      sh_rr[o] = (t < TOPK) ? 1.f : 0.f;  // desc rank < 10 -> top-10
    }
    float inv = 1.f / fmaxf(sqrtf(ssq), 1e-8f);  // orig item t (early ssq)
    sh_inv[t] = inv;
    float om = 1.f - ssq * inv * inv;  // 1 - ||n||^2 for ORIG item t
    __syncthreads();
    float arj = sh_aux[t], rrj = sh_rr[t];
    float r1 = arj, r2 = arj * arj, r3 = arj * arj * om, r4v = rrj,
          r5v = rrj * om;
#pragma unroll
    for (int mm = 32; mm >= 1; mm >>= 1) {
      r1 += __shfl_xor(r1, mm, 64);
      r2 += __shfl_xor(r2, mm, 64);
      r3 += __shfl_xor(r3, mm, 64);
      r4v += __shfl_xor(r4v, mm, 64);
      r5v += __shfl_xor(r5v, mm, 64);
    }
    if (ln == 0) {
      sh_w1[wv] = r1; sh_w2[wv] = r2; sh_w3[wv] = r3;
      sh_w4[wv] = r4v; sh_w5[wv] = r5v;
    }
    // V = sum_j a_j * n_j (64-dim): wave wv handles 64 j's, lane = feature
    const float* bu = batch + (size_t)u * N * F_STRIDE;
    float va = 0.f, vr = 0.f;
#pragma unroll 8
    for (int jj = 0; jj < 64; jj++) {
      int j2 = (wv << 6) + jj;
      float x = bu[(size_t)j2 * F_STRIDE + ln] * sh_inv[j2];
      va = fmaf(sh_aux[j2], x, va);
      vr = fmaf(sh_rr[j2], x, vr);
    }
    sh_pA[t] = va;
    sh_pB[t] = vr;
    __syncthreads();
    float qa = 0.f, qr = 0.f;
    if (t < 64) {
      float VA = 0.f, VR = 0.f;
#pragma unroll
      for (int c2 = 0; c2 < 8; c2++) {
        VA += sh_pA[c2 * 64 + t];
        VR += sh_pB[c2 * 64 + t];
      }
      qa = VA * VA;
      qr = VR * VR;
    }
#pragma unroll
    for (int mm = 32; mm >= 1; mm >>= 1) {
      qa += __shfl_xor(qa, mm, 64);
      qr += __shfl_xor(qr, mm, 64);
    }
    if (t == 0) {  // qa/qr complete in wave 0; sh_w* visible since last bar
      float S1a = 0.f, S2a = 0.f, DA = 0.f, S1r = 0.f, DR = 0.f;
#pragma unroll
      for (int w2 = 0; w2 < 8; w2++) {
        S1a += sh_w1[w2]; S2a += sh_w2[w2]; DA += sh_w3[w2];
        S1r += sh_w4[w2]; DR += sh_w5[w2];
      }
      // sum_{i<j} a_i a_j (1 - n_i.n_j) = 0.5*(S1^2 - ||V||^2 - diag)
      float numA = 0.5f * (S1a * S1a - qa - DA);
      float denA = 0.5f * (S1a * S1a - S2a);
      out[2 * U_CNT + u] = numA / denA;
      float numR = 0.5f * (S1r * S1r - qr - DR);
      float denR = 0.5f * (S1r * S1r - S1r);
      out[3 * U_CNT + u] = numR / denR;
    }
  }
}

extern "C" void kernel_launch(void* const* d_in, const int* in_sizes, int n_in,
                              void* d_out, int out_size, void* d_ws,
                              size_t ws_size, hipStream_t stream) {
  (void)in_sizes; (void)n_in; (void)d_ws; (void)ws_size; (void)out_size;
  const float* batch = (const float*)d_in[0];
  const float* sdiv = (const float*)d_in[1];
  const float* sndcg = (const float*)d_in[2];
  const float* rel = (const float*)d_in[3];
  float* out = (float*)d_out;
  loss_kernel<<<dim3(U_CNT * 2), dim3(N), 0, stream>>>(batch, sdiv, sndcg, rel,
                                                       out);
}